// Round 3
// baseline (703.827 us; speedup 1.0000x reference)
//
#include <hip/hip_runtime.h>

#define NB 512
#define NT 1024
#define NK 48
#define NEGV -10000.0f
#define S_START 46
#define S_END 47

extern "C" __global__ __launch_bounds__(128, 1)
void crf_fused(const float* __restrict__ feats, const float* __restrict__ trans,
               float* __restrict__ out)
{
    // wave 0: CRF forward (logZ).  wave 1: Viterbi + backtrace.
    // All LDS traffic intra-wave (DS pipe in-order per wave): no s_barrier.
    __shared__ unsigned char bp[NT * NK];        // 48 KB backpointers (wave 1)
    __shared__ unsigned char comp[64 * NK];      // composed chunk tag-maps
    __shared__ unsigned char boundary[64];       // chunk-entry tags
    __shared__ float eabuf[64];                  // forward broadcast buffer
    __shared__ float vbuf[64];                   // viterbi broadcast buffer

    const int b = blockIdx.x;
    const int wave = threadIdx.x >> 6;
    const int lane = threadIdx.x & 63;
    const bool act = lane < NK;
    const int LL = act ? lane : (NK - 1);        // clamped state: lanes 48..63 mirror 47
    const float* f = feats + (size_t)b * NT * NK;
    const float* fb = f + LL;                    // per-lane column base (always in-bounds)

    float tEnd = NEGV;
    if (act && lane != S_END) tEnd = trans[S_END * NK + lane];

    if (wave == 0) {
        // ---------------- forward: alpha' = M + log(E . exp(alpha-M)) + feat
        // M maintained one step stale = EXACT max of prev alpha (round-1 semantics)
        float Erow[NK];
        {
            const bool rowdead = (lane == S_START);
            const float4* r4 = (const float4*)(trans + LL * NK);
            #pragma unroll
            for (int q = 0; q < NK / 4; ++q) {
                float4 r = r4[q];
                const int c = 4 * q;
                Erow[c + 0] = (rowdead || c + 0 == S_END) ? 0.0f : __expf(r.x);
                Erow[c + 1] = (rowdead || c + 1 == S_END) ? 0.0f : __expf(r.y);
                Erow[c + 2] = (rowdead || c + 2 == S_END) ? 0.0f : __expf(r.z);
                Erow[c + 3] = (rowdead || c + 3 == S_END) ? 0.0f : __expf(r.w);
            }
        }
        float u = (lane == S_START) ? 0.0f : NEGV;
        float Muni = 0.0f;
        eabuf[lane] = __expf(u);                 // exp(0)=1 at START, else 0
        __builtin_amdgcn_wave_barrier();

        float fr0 = fb[0 * NK], fr1 = fb[1 * NK], fr2 = fb[2 * NK], fr3 = fb[3 * NK];

        auto fstep = [&](float fc) {
            const float4* e4 = (const float4*)eabuf;
            float a0 = 0.f, a1 = 0.f, a2 = 0.f, a3 = 0.f;
            float mq[12];
            #pragma unroll
            for (int q = 0; q < 12; ++q) {
                float4 r = e4[q];
                a0 = fmaf(Erow[4 * q + 0], r.x, a0);
                a1 = fmaf(Erow[4 * q + 1], r.y, a1);
                a2 = fmaf(Erow[4 * q + 2], r.z, a2);
                a3 = fmaf(Erow[4 * q + 3], r.w, a3);
                mq[q] = fmaxf(fmaxf(r.x, r.y), fmaxf(r.z, r.w));
            }
            float acc = (a0 + a1) + (a2 + a3);   // same grouping as round 1: bit-exact
            // exact max of ea (max is exactly associative: tree shape irrelevant)
            float m01 = fmaxf(fmaxf(mq[0], mq[1]), fmaxf(mq[2], mq[3]));
            float m23 = fmaxf(fmaxf(mq[4], mq[5]), fmaxf(mq[6], mq[7]));
            float m45 = fmaxf(fmaxf(mq[8], mq[9]), fmaxf(mq[10], mq[11]));
            float m_e = fmaxf(fmaxf(m01, m23), m45);

            float dM = __logf(m_e);              // M_{t+1} = M_t + dM  (exact stale max)
            Muni += dM;
            u = __logf(acc) + fc - dM;           // log(0)=-inf propagates cleanly
            __builtin_amdgcn_wave_barrier();
            eabuf[lane] = __expf(u);
            __builtin_amdgcn_wave_barrier();
        };

        for (int t = 0; t < NT; t += 4) {
            { float fc = fr0; int nr = (t + 4 < NT) ? t + 4 : NT - 1; fr0 = fb[nr * NK]; fstep(fc); }
            { float fc = fr1; int nr = (t + 5 < NT) ? t + 5 : NT - 1; fr1 = fb[nr * NK]; fstep(fc); }
            { float fc = fr2; int nr = (t + 6 < NT) ? t + 6 : NT - 1; fr2 = fb[nr * NK]; fstep(fc); }
            { float fc = fr3; int nr = (t + 7 < NT) ? t + 7 : NT - 1; fr3 = fb[nr * NK]; fstep(fc); }
        }
        // logz = Muni + logsumexp(u + tEnd)
        float x = act ? (u + tEnd) : -INFINITY;
        float M2 = x;
        #pragma unroll
        for (int off = 32; off >= 1; off >>= 1)
            M2 = fmaxf(M2, __shfl_xor(M2, off, 64));
        float e = __expf(x - M2);
        #pragma unroll
        for (int off = 32; off >= 1; off >>= 1)
            e += __shfl_xor(e, off, 64);
        if (lane == 0) out[b] = Muni + M2 + __logf(e);
    } else {
        // ---------------- viterbi: exact fp32, reference op order
        float trow[NK];
        {
            const bool rowdead = (lane == S_START);
            const float4* r4 = (const float4*)(trans + LL * NK);
            #pragma unroll
            for (int q = 0; q < NK / 4; ++q) {
                float4 r = r4[q];
                const int c = 4 * q;
                trow[c + 0] = (rowdead || c + 0 == S_END) ? NEGV : r.x;
                trow[c + 1] = (rowdead || c + 1 == S_END) ? NEGV : r.y;
                trow[c + 2] = (rowdead || c + 2 == S_END) ? NEGV : r.z;
                trow[c + 3] = (rowdead || c + 3 == S_END) ? NEGV : r.w;
            }
        }
        float v = (lane == S_START) ? 0.0f : NEGV;
        vbuf[lane] = v;
        __builtin_amdgcn_wave_barrier();

        float fr0 = fb[0 * NK], fr1 = fb[1 * NK], fr2 = fb[2 * NK], fr3 = fb[3 * NK];

        // merge: keep right only if strictly greater => tie keeps lower index
        // (subtrees span contiguous ascending index ranges => np.argmax semantics)
        auto vstep = [&](float fc, int tt) {
            const float4* v4 = (const float4*)vbuf;
            float cv[4]; int ci[4];              // per-chunk (value, index)
            #pragma unroll
            for (int c = 0; c < 4; ++c) {
                float l[12]; int li[12];
                #pragma unroll
                for (int j = 0; j < 3; ++j) {
                    const int q = 3 * c + j;
                    float4 r = v4[q];
                    float s0 = r.x + trow[4 * q + 0];
                    float s1 = r.y + trow[4 * q + 1];
                    float s2 = r.z + trow[4 * q + 2];
                    float s3 = r.w + trow[4 * q + 3];
                    bool t01 = s1 > s0;
                    l[4 * j + 0] = t01 ? s1 : s0;  li[4 * j + 0] = t01 ? 4 * q + 1 : 4 * q + 0;
                    bool t23 = s3 > s2;
                    l[4 * j + 1] = t23 ? s3 : s2;  li[4 * j + 1] = t23 ? 4 * q + 3 : 4 * q + 2;
                    // positions 4j+2,4j+3 unused at this level
                }
                // 6 pair-winners live in l[0],l[1],l[4],l[5],l[8],l[9]
                bool ta = l[1] > l[0];  float w0 = ta ? l[1] : l[0];  int i0 = ta ? li[1] : li[0];
                bool tb = l[5] > l[4];  float w1 = tb ? l[5] : l[4];  int i1 = tb ? li[5] : li[4];
                bool tc = l[9] > l[8];  float w2 = tc ? l[9] : l[8];  int i2 = tc ? li[9] : li[8];
                bool td = w1 > w0;      float w01 = td ? w1 : w0;     int i01 = td ? i1 : i0;
                bool te = w2 > w01;     cv[c] = te ? w2 : w01;        ci[c] = te ? i2 : i01;
            }
            bool tA = cv[1] > cv[0];  float vA = tA ? cv[1] : cv[0];  int iA = tA ? ci[1] : ci[0];
            bool tB = cv[3] > cv[2];  float vB = tB ? cv[3] : cv[2];  int iB = tB ? ci[3] : ci[2];
            bool tC = vB > vA;        float best = tC ? vB : vA;      int bi = tC ? iB : iA;

            bp[tt * NK + LL] = (unsigned char)bi; // lanes 47..63: same addr, same value
            v = best + fc;                        // reference order: +feat after argmax
            __builtin_amdgcn_wave_barrier();
            vbuf[lane] = v;
            __builtin_amdgcn_wave_barrier();
        };

        for (int t = 0; t < NT; t += 4) {
            { float fc = fr0; int nr = (t + 4 < NT) ? t + 4 : NT - 1; fr0 = fb[nr * NK]; vstep(fc, t + 0); }
            { float fc = fr1; int nr = (t + 5 < NT) ? t + 5 : NT - 1; fr1 = fb[nr * NK]; vstep(fc, t + 1); }
            { float fc = fr2; int nr = (t + 6 < NT) ? t + 6 : NT - 1; fr2 = fb[nr * NK]; vstep(fc, t + 2); }
            { float fc = fr3; int nr = (t + 7 < NT) ? t + 7 : NT - 1; fr3 = fb[nr * NK]; vstep(fc, t + 3); }
        }
        // termination: term = v + trans[END]; first-occurrence argmax
        float xv = act ? (v + tEnd) : -INFINITY;
        int idx = act ? lane : 63;
        float val = xv;
        #pragma unroll
        for (int off = 32; off >= 1; off >>= 1) {
            float ov = __shfl_xor(val, off, 64);
            int   oi = __shfl_xor(idx, off, 64);
            if (ov > val || (ov == val && oi < idx)) { val = ov; idx = oi; }
        }
        if (lane == 0) out[NB + b] = val;
        const int last = idx;

        // ---- chunk-composed backtrace (all intra-wave LDS, in-order DS pipe)
        __builtin_amdgcn_wave_barrier();
        int cur[NK];
        #pragma unroll
        for (int k = 0; k < NK; ++k) cur[k] = k;
        const int tbase = lane * 16;                 // 64 chunks of 16 steps
        for (int i = 15; i >= 0; --i) {
            const int t = tbase + i;
            #pragma unroll
            for (int k = 0; k < NK; ++k) cur[k] = bp[t * NK + cur[k]];
        }
        #pragma unroll
        for (int k = 0; k < NK; ++k) comp[lane * NK + k] = (unsigned char)cur[k];
        __builtin_amdgcn_wave_barrier();

        if (lane == 0) {                             // serial chase over 64 maps
            int tag = last;
            for (int l = 63; l >= 0; --l) {
                boundary[l] = (unsigned char)tag;
                tag = comp[l * NK + tag];
            }
        }
        __builtin_amdgcn_wave_barrier();

        int tag = boundary[lane];
        float* pout = out + 2 * NB + (size_t)b * NT;
        for (int i = 15; i >= 0; --i) {              // re-expand: path[t]=tag, then step
            const int t = tbase + i;
            pout[t] = (float)tag;
            tag = bp[t * NK + tag];
        }
    }
}

extern "C" void kernel_launch(void* const* d_in, const int* in_sizes, int n_in,
                              void* d_out, int out_size, void* d_ws, size_t ws_size,
                              hipStream_t stream) {
    (void)in_sizes; (void)n_in; (void)d_ws; (void)ws_size; (void)out_size;
    const float* feats = (const float*)d_in[0];
    const float* trans = (const float*)d_in[1];
    float* out = (float*)d_out;
    crf_fused<<<dim3(NB), dim3(128), 0, stream>>>(feats, trans, out);
}

// Round 4
// 634.815 us; speedup vs baseline: 1.1087x; 1.1087x over previous
//
#include <hip/hip_runtime.h>

#define NB 512
#define NT 1024
#define NK 48
#define NEGV -10000.0f
#define S_START 46
#define S_END 47

extern "C" __global__ __launch_bounds__(128, 1)
void crf_fused(const float* __restrict__ feats, const float* __restrict__ trans,
               float* __restrict__ out)
{
    // wave 0: CRF forward (logZ).  wave 1: Viterbi + backtrace.
    // Intra-wave LDS ordering is guaranteed by the in-order DS pipe + compiler
    // alias analysis on the same array -> NO barriers inside the step loops.
    __shared__ unsigned char bp[NT * NK];        // 48 KB backpointers (wave 1)
    __shared__ unsigned char comp[64 * NK];      // composed chunk tag-maps
    __shared__ unsigned char boundary[64];       // chunk-entry tags
    __shared__ float eabuf[64];                  // forward broadcast buffer
    __shared__ float vbuf[64];                   // viterbi broadcast buffer

    const int b = blockIdx.x;
    const int wave = threadIdx.x >> 6;
    const int lane = threadIdx.x & 63;
    const bool act = lane < NK;
    const int LL = act ? lane : (NK - 1);        // clamped state: lanes 48..63 mirror 47
    const float* f = feats + (size_t)b * NT * NK;
    const float* fb = f + LL;                    // per-lane column base (always in-bounds)

    float tEnd = NEGV;
    if (act && lane != S_END) tEnd = trans[S_END * NK + lane];

    if (wave == 0) {
        // ---------------- forward: alpha' = M + log(E . exp(alpha-M)) + feat
        // M one step stale = EXACT max of prev alpha (absmax-0 heritage from R1/R3)
        float Erow[NK];
        {
            const bool rowdead = (lane == S_START);
            const float4* r4 = (const float4*)(trans + LL * NK);
            #pragma unroll
            for (int q = 0; q < NK / 4; ++q) {
                float4 r = r4[q];
                const int c = 4 * q;
                Erow[c + 0] = (rowdead || c + 0 == S_END) ? 0.0f : __expf(r.x);
                Erow[c + 1] = (rowdead || c + 1 == S_END) ? 0.0f : __expf(r.y);
                Erow[c + 2] = (rowdead || c + 2 == S_END) ? 0.0f : __expf(r.z);
                Erow[c + 3] = (rowdead || c + 3 == S_END) ? 0.0f : __expf(r.w);
            }
        }
        float u = (lane == S_START) ? 0.0f : NEGV;
        float Muni = 0.0f;
        eabuf[lane] = __expf(u);                 // exp(0)=1 at START, else 0

        float fr0 = fb[0 * NK], fr1 = fb[1 * NK], fr2 = fb[2 * NK], fr3 = fb[3 * NK];

        auto fstep = [&](float fc) {
            const float4* e4 = (const float4*)eabuf;
            float a0 = 0.f, a1 = 0.f, a2 = 0.f, a3 = 0.f;
            float mq[12];
            #pragma unroll
            for (int q = 0; q < 12; ++q) {
                float4 r = e4[q];
                a0 = fmaf(Erow[4 * q + 0], r.x, a0);
                a1 = fmaf(Erow[4 * q + 1], r.y, a1);
                a2 = fmaf(Erow[4 * q + 2], r.z, a2);
                a3 = fmaf(Erow[4 * q + 3], r.w, a3);
                mq[q] = fmaxf(fmaxf(r.x, r.y), fmaxf(r.z, r.w));
            }
            float acc = (a0 + a1) + (a2 + a3);   // bit-exact grouping (R1/R3)
            float m01 = fmaxf(fmaxf(mq[0], mq[1]), fmaxf(mq[2], mq[3]));
            float m23 = fmaxf(fmaxf(mq[4], mq[5]), fmaxf(mq[6], mq[7]));
            float m45 = fmaxf(fmaxf(mq[8], mq[9]), fmaxf(mq[10], mq[11]));
            float m_e = fmaxf(fmaxf(m01, m23), m45);

            float dM = __logf(m_e);              // exact stale max anchor
            u = __logf(acc) + fc - dM;
            eabuf[lane] = __expf(u);             // store ASAP: next read depends on it
            Muni += dM;                          // off-chain, after the store
        };

        for (int t = 0; t < NT; t += 4) {
            { float fc = fr0; int nr = (t + 4 < NT) ? t + 4 : NT - 1; fr0 = fb[nr * NK]; fstep(fc); }
            { float fc = fr1; int nr = (t + 5 < NT) ? t + 5 : NT - 1; fr1 = fb[nr * NK]; fstep(fc); }
            { float fc = fr2; int nr = (t + 6 < NT) ? t + 6 : NT - 1; fr2 = fb[nr * NK]; fstep(fc); }
            { float fc = fr3; int nr = (t + 7 < NT) ? t + 7 : NT - 1; fr3 = fb[nr * NK]; fstep(fc); }
        }
        // logz = Muni + logsumexp(u + tEnd)
        float x = act ? (u + tEnd) : -INFINITY;
        float M2 = x;
        #pragma unroll
        for (int off = 32; off >= 1; off >>= 1)
            M2 = fmaxf(M2, __shfl_xor(M2, off, 64));
        float e = __expf(x - M2);
        #pragma unroll
        for (int off = 32; off >= 1; off >>= 1)
            e += __shfl_xor(e, off, 64);
        if (lane == 0) out[b] = Muni + M2 + __logf(e);
    } else {
        // ---------------- viterbi: exact fp32, reference op order
        float trow[NK];
        {
            const bool rowdead = (lane == S_START);
            const float4* r4 = (const float4*)(trans + LL * NK);
            #pragma unroll
            for (int q = 0; q < NK / 4; ++q) {
                float4 r = r4[q];
                const int c = 4 * q;
                trow[c + 0] = (rowdead || c + 0 == S_END) ? NEGV : r.x;
                trow[c + 1] = (rowdead || c + 1 == S_END) ? NEGV : r.y;
                trow[c + 2] = (rowdead || c + 2 == S_END) ? NEGV : r.z;
                trow[c + 3] = (rowdead || c + 3 == S_END) ? NEGV : r.w;
            }
        }
        float v = (lane == S_START) ? 0.0f : NEGV;
        vbuf[lane] = v;

        float fr0 = fb[0 * NK], fr1 = fb[1 * NK], fr2 = fb[2 * NK], fr3 = fb[3 * NK];
        const int big = 63;

        auto vstep = [&](float fc, int tt) {
            float s[NK];
            {
                const float4* v4 = (const float4*)vbuf;
                #pragma unroll
                for (int q = 0; q < NK / 4; ++q) {
                    float4 r = v4[q];
                    s[4 * q + 0] = r.x + trow[4 * q + 0];
                    s[4 * q + 1] = r.y + trow[4 * q + 1];
                    s[4 * q + 2] = r.z + trow[4 * q + 2];
                    s[4 * q + 3] = r.w + trow[4 * q + 3];
                }
            }
            // exact max via tree (identical shape to R2; max exactly associative)
            float m16[16];
            #pragma unroll
            for (int i = 0; i < 16; ++i)
                m16[i] = fmaxf(fmaxf(s[3 * i], s[3 * i + 1]), s[3 * i + 2]);
            float m6[6];
            #pragma unroll
            for (int i = 0; i < 5; ++i)
                m6[i] = fmaxf(fmaxf(m16[3 * i], m16[3 * i + 1]), m16[3 * i + 2]);
            m6[5] = m16[15];
            float best = fmaxf(fmaxf(fmaxf(m6[0], m6[1]), m6[2]),
                               fmaxf(fmaxf(m6[3], m6[4]), m6[5]));

            // ---- critical recurrence: store the new v IMMEDIATELY
            v = best + fc;                       // reference order: +feat after max
            vbuf[lane] = v;                      // next step's reads wait only on this

            // ---- off-chain: first-occurrence argmax (np.argmax), then bp store.
            // Sits after the vbuf write so its ~290 issue cycles overlap the
            // LDS round-trip + next step's read latency.
            int ix[NK];
            #pragma unroll
            for (int p = 0; p < NK; ++p)
                ix[p] = (s[p] != best) ? big : p;
            int n16[16];
            #pragma unroll
            for (int i = 0; i < 16; ++i)
                n16[i] = min(min(ix[3 * i], ix[3 * i + 1]), ix[3 * i + 2]);
            int n6[6];
            #pragma unroll
            for (int i = 0; i < 5; ++i)
                n6[i] = min(min(n16[3 * i], n16[3 * i + 1]), n16[3 * i + 2]);
            n6[5] = n16[15];
            int bi = min(min(min(n6[0], n6[1]), n6[2]),
                         min(min(n6[3], n6[4]), n6[5]));
            bp[tt * NK + LL] = (unsigned char)bi; // lanes 47..63: same addr, same value
        };

        for (int t = 0; t < NT; t += 4) {
            { float fc = fr0; int nr = (t + 4 < NT) ? t + 4 : NT - 1; fr0 = fb[nr * NK]; vstep(fc, t + 0); }
            { float fc = fr1; int nr = (t + 5 < NT) ? t + 5 : NT - 1; fr1 = fb[nr * NK]; vstep(fc, t + 1); }
            { float fc = fr2; int nr = (t + 6 < NT) ? t + 6 : NT - 1; fr2 = fb[nr * NK]; vstep(fc, t + 2); }
            { float fc = fr3; int nr = (t + 7 < NT) ? t + 7 : NT - 1; fr3 = fb[nr * NK]; vstep(fc, t + 3); }
        }
        // termination: term = v + trans[END]; first-occurrence argmax
        float xv = act ? (v + tEnd) : -INFINITY;
        int idx = act ? lane : 63;
        float val = xv;
        #pragma unroll
        for (int off = 32; off >= 1; off >>= 1) {
            float ov = __shfl_xor(val, off, 64);
            int   oi = __shfl_xor(idx, off, 64);
            if (ov > val || (ov == val && oi < idx)) { val = ov; idx = oi; }
        }
        if (lane == 0) out[NB + b] = val;
        const int last = idx;

        // ---- chunk-composed backtrace (all intra-wave LDS, in-order DS pipe)
        __builtin_amdgcn_wave_barrier();
        int cur[NK];
        #pragma unroll
        for (int k = 0; k < NK; ++k) cur[k] = k;
        const int tbase = lane * 16;                 // 64 chunks of 16 steps
        for (int i = 15; i >= 0; --i) {
            const int t = tbase + i;
            #pragma unroll
            for (int k = 0; k < NK; ++k) cur[k] = bp[t * NK + cur[k]];
        }
        #pragma unroll
        for (int k = 0; k < NK; ++k) comp[lane * NK + k] = (unsigned char)cur[k];
        __builtin_amdgcn_wave_barrier();

        if (lane == 0) {                             // serial chase over 64 maps
            int tag = last;
            for (int l = 63; l >= 0; --l) {
                boundary[l] = (unsigned char)tag;
                tag = comp[l * NK + tag];
            }
        }
        __builtin_amdgcn_wave_barrier();

        int tag = boundary[lane];
        float* pout = out + 2 * NB + (size_t)b * NT;
        for (int i = 15; i >= 0; --i) {              // re-expand: path[t]=tag, then step
            const int t = tbase + i;
            pout[t] = (float)tag;
            tag = bp[t * NK + tag];
        }
    }
}

extern "C" void kernel_launch(void* const* d_in, const int* in_sizes, int n_in,
                              void* d_out, int out_size, void* d_ws, size_t ws_size,
                              hipStream_t stream) {
    (void)in_sizes; (void)n_in; (void)d_ws; (void)ws_size; (void)out_size;
    const float* feats = (const float*)d_in[0];
    const float* trans = (const float*)d_in[1];
    float* out = (float*)d_out;
    crf_fused<<<dim3(NB), dim3(128), 0, stream>>>(feats, trans, out);
}

// Round 5
// 605.163 us; speedup vs baseline: 1.1630x; 1.0490x over previous
//
#include <hip/hip_runtime.h>

#define NB 512
#define NT 1024
#define NK 48
#define NEGV -10000.0f
#define S_START 46
#define S_END 47

extern "C" __global__ __launch_bounds__(128, 1)
void crf_fused(const float* __restrict__ feats, const float* __restrict__ trans,
               float* __restrict__ out)
{
    // wave 0: CRF forward (logZ).  wave 1: Viterbi + backtrace.
    // Pipelined-read structure: each step stores its new state to LDS, then
    // IMMEDIATELY issues the next step's 12 ds_read_b128, THEN does the
    // off-chain work (argmax/bp for viterbi, Muni for forward) while the
    // reads are in flight. In-order DS pipe guarantees read-after-write.
    __shared__ unsigned char bp[NT * NK];        // 48 KB backpointers (wave 1)
    __shared__ unsigned char comp[64 * NK];      // composed chunk tag-maps
    __shared__ unsigned char boundary[64];       // chunk-entry tags
    __shared__ float eabuf[64];                  // forward broadcast buffer
    __shared__ float vbuf[64];                   // viterbi broadcast buffer

    const int b = blockIdx.x;
    const int wave = threadIdx.x >> 6;
    const int lane = threadIdx.x & 63;
    const bool act = lane < NK;
    const int LL = act ? lane : (NK - 1);        // clamped state: lanes 48..63 mirror 47
    const float* f = feats + (size_t)b * NT * NK;
    const float* fb = f + LL;                    // per-lane column base (always in-bounds)

    float tEnd = NEGV;
    if (act && lane != S_END) tEnd = trans[S_END * NK + lane];

    if (wave == 0) {
        // ---------------- forward: alpha' = M + log(E . exp(alpha-M)) + feat
        // M one step stale = EXACT max of prev alpha (absmax-0 heritage R1/R3/R4)
        float Erow[NK];
        {
            const bool rowdead = (lane == S_START);
            const float4* r4 = (const float4*)(trans + LL * NK);
            #pragma unroll
            for (int q = 0; q < NK / 4; ++q) {
                float4 r = r4[q];
                const int c = 4 * q;
                Erow[c + 0] = (rowdead || c + 0 == S_END) ? 0.0f : __expf(r.x);
                Erow[c + 1] = (rowdead || c + 1 == S_END) ? 0.0f : __expf(r.y);
                Erow[c + 2] = (rowdead || c + 2 == S_END) ? 0.0f : __expf(r.z);
                Erow[c + 3] = (rowdead || c + 3 == S_END) ? 0.0f : __expf(r.w);
            }
        }
        float u = (lane == S_START) ? 0.0f : NEGV;
        float Muni = 0.0f;
        eabuf[lane] = __expf(u);                 // exp(0)=1 at START, else 0

        const float4* e4 = (const float4*)eabuf;
        float4 rq[12];
        #pragma unroll
        for (int q = 0; q < 12; ++q) rq[q] = e4[q];   // prime (after store: in-order)

        float fr0 = fb[0 * NK], fr1 = fb[1 * NK], fr2 = fb[2 * NK], fr3 = fb[3 * NK];

        auto fstep = [&](float fc) {
            float a0 = 0.f, a1 = 0.f, a2 = 0.f, a3 = 0.f;
            float mq[12];
            #pragma unroll
            for (int q = 0; q < 12; ++q) {
                float4 r = rq[q];
                a0 = fmaf(Erow[4 * q + 0], r.x, a0);
                a1 = fmaf(Erow[4 * q + 1], r.y, a1);
                a2 = fmaf(Erow[4 * q + 2], r.z, a2);
                a3 = fmaf(Erow[4 * q + 3], r.w, a3);
                mq[q] = fmaxf(fmaxf(r.x, r.y), fmaxf(r.z, r.w));
            }
            float acc = (a0 + a1) + (a2 + a3);   // bit-exact grouping (R1/R3/R4)
            float m01 = fmaxf(fmaxf(mq[0], mq[1]), fmaxf(mq[2], mq[3]));
            float m23 = fmaxf(fmaxf(mq[4], mq[5]), fmaxf(mq[6], mq[7]));
            float m45 = fmaxf(fmaxf(mq[8], mq[9]), fmaxf(mq[10], mq[11]));
            float m_e = fmaxf(fmaxf(m01, m23), m45);

            float dM = __logf(m_e);              // exact stale max anchor
            u = __logf(acc) + fc - dM;
            __builtin_amdgcn_wave_barrier();
            eabuf[lane] = __expf(u);             // chain store
            #pragma unroll
            for (int q = 0; q < 12; ++q) rq[q] = e4[q];  // next step's reads, ASAP
            __builtin_amdgcn_wave_barrier();
            Muni += dM;                          // off-chain, during read flight
        };

        for (int t = 0; t < NT; t += 4) {
            { float fc = fr0; int nr = (t + 4 < NT) ? t + 4 : NT - 1; fr0 = fb[nr * NK]; fstep(fc); }
            { float fc = fr1; int nr = (t + 5 < NT) ? t + 5 : NT - 1; fr1 = fb[nr * NK]; fstep(fc); }
            { float fc = fr2; int nr = (t + 6 < NT) ? t + 6 : NT - 1; fr2 = fb[nr * NK]; fstep(fc); }
            { float fc = fr3; int nr = (t + 7 < NT) ? t + 7 : NT - 1; fr3 = fb[nr * NK]; fstep(fc); }
        }
        // logz = Muni + logsumexp(u + tEnd)
        float x = act ? (u + tEnd) : -INFINITY;
        float M2 = x;
        #pragma unroll
        for (int off = 32; off >= 1; off >>= 1)
            M2 = fmaxf(M2, __shfl_xor(M2, off, 64));
        float e = __expf(x - M2);
        #pragma unroll
        for (int off = 32; off >= 1; off >>= 1)
            e += __shfl_xor(e, off, 64);
        if (lane == 0) out[b] = Muni + M2 + __logf(e);
    } else {
        // ---------------- viterbi: exact fp32, reference op order
        float trow[NK];
        {
            const bool rowdead = (lane == S_START);
            const float4* r4 = (const float4*)(trans + LL * NK);
            #pragma unroll
            for (int q = 0; q < NK / 4; ++q) {
                float4 r = r4[q];
                const int c = 4 * q;
                trow[c + 0] = (rowdead || c + 0 == S_END) ? NEGV : r.x;
                trow[c + 1] = (rowdead || c + 1 == S_END) ? NEGV : r.y;
                trow[c + 2] = (rowdead || c + 2 == S_END) ? NEGV : r.z;
                trow[c + 3] = (rowdead || c + 3 == S_END) ? NEGV : r.w;
            }
        }
        float v = (lane == S_START) ? 0.0f : NEGV;
        vbuf[lane] = v;

        const float4* v4 = (const float4*)vbuf;
        float4 rq[12];
        #pragma unroll
        for (int q = 0; q < 12; ++q) rq[q] = v4[q];   // prime (after store: in-order)

        float fr0 = fb[0 * NK], fr1 = fb[1 * NK], fr2 = fb[2 * NK], fr3 = fb[3 * NK];
        const int big = 63;

        auto vstep = [&](float fc, int tt) {
            float s[NK];
            #pragma unroll
            for (int q = 0; q < 12; ++q) {
                float4 r = rq[q];
                s[4 * q + 0] = r.x + trow[4 * q + 0];
                s[4 * q + 1] = r.y + trow[4 * q + 1];
                s[4 * q + 2] = r.z + trow[4 * q + 2];
                s[4 * q + 3] = r.w + trow[4 * q + 3];
            }
            // exact max via tree (max exactly associative; identical to np.max)
            float m16[16];
            #pragma unroll
            for (int i = 0; i < 16; ++i)
                m16[i] = fmaxf(fmaxf(s[3 * i], s[3 * i + 1]), s[3 * i + 2]);
            float m6[6];
            #pragma unroll
            for (int i = 0; i < 5; ++i)
                m6[i] = fmaxf(fmaxf(m16[3 * i], m16[3 * i + 1]), m16[3 * i + 2]);
            m6[5] = m16[15];
            float best = fmaxf(fmaxf(fmaxf(m6[0], m6[1]), m6[2]),
                               fmaxf(fmaxf(m6[3], m6[4]), m6[5]));

            // ---- critical recurrence: store new v, then ISSUE next step's reads
            v = best + fc;                       // reference order: +feat after max
            __builtin_amdgcn_wave_barrier();
            vbuf[lane] = v;
            #pragma unroll
            for (int q = 0; q < 12; ++q) rq[q] = v4[q];  // in DS queue behind store
            __builtin_amdgcn_wave_barrier();

            // ---- off-chain: argmax + bp store execute while reads are in flight
            int ix[NK];
            #pragma unroll
            for (int p = 0; p < NK; ++p)
                ix[p] = (s[p] != best) ? big : p;
            int n16[16];
            #pragma unroll
            for (int i = 0; i < 16; ++i)
                n16[i] = min(min(ix[3 * i], ix[3 * i + 1]), ix[3 * i + 2]);
            int n6[6];
            #pragma unroll
            for (int i = 0; i < 5; ++i)
                n6[i] = min(min(n16[3 * i], n16[3 * i + 1]), n16[3 * i + 2]);
            n6[5] = n16[15];
            int bi = min(min(min(n6[0], n6[1]), n6[2]),
                         min(min(n6[3], n6[4]), n6[5]));
            bp[tt * NK + LL] = (unsigned char)bi; // queued behind issued reads: no stall
        };

        for (int t = 0; t < NT; t += 4) {
            { float fc = fr0; int nr = (t + 4 < NT) ? t + 4 : NT - 1; fr0 = fb[nr * NK]; vstep(fc, t + 0); }
            { float fc = fr1; int nr = (t + 5 < NT) ? t + 5 : NT - 1; fr1 = fb[nr * NK]; vstep(fc, t + 1); }
            { float fc = fr2; int nr = (t + 6 < NT) ? t + 6 : NT - 1; fr2 = fb[nr * NK]; vstep(fc, t + 2); }
            { float fc = fr3; int nr = (t + 7 < NT) ? t + 7 : NT - 1; fr3 = fb[nr * NK]; vstep(fc, t + 3); }
        }
        // termination: term = v + trans[END]; first-occurrence argmax
        float xv = act ? (v + tEnd) : -INFINITY;
        int idx = act ? lane : 63;
        float val = xv;
        #pragma unroll
        for (int off = 32; off >= 1; off >>= 1) {
            float ov = __shfl_xor(val, off, 64);
            int   oi = __shfl_xor(idx, off, 64);
            if (ov > val || (ov == val && oi < idx)) { val = ov; idx = oi; }
        }
        if (lane == 0) out[NB + b] = val;
        const int last = idx;

        // ---- chunk-composed backtrace (all intra-wave LDS, in-order DS pipe)
        __builtin_amdgcn_wave_barrier();
        int cur[NK];
        #pragma unroll
        for (int k = 0; k < NK; ++k) cur[k] = k;
        const int tbase = lane * 16;                 // 64 chunks of 16 steps
        for (int i = 15; i >= 0; --i) {
            const int t = tbase + i;
            #pragma unroll
            for (int k = 0; k < NK; ++k) cur[k] = bp[t * NK + cur[k]];
        }
        #pragma unroll
        for (int k = 0; k < NK; ++k) comp[lane * NK + k] = (unsigned char)cur[k];
        __builtin_amdgcn_wave_barrier();

        if (lane == 0) {                             // serial chase over 64 maps
            int tag = last;
            for (int l = 63; l >= 0; --l) {
                boundary[l] = (unsigned char)tag;
                tag = comp[l * NK + tag];
            }
        }
        __builtin_amdgcn_wave_barrier();

        int tag = boundary[lane];
        float* pout = out + 2 * NB + (size_t)b * NT;
        for (int i = 15; i >= 0; --i) {              // re-expand: path[t]=tag, then step
            const int t = tbase + i;
            pout[t] = (float)tag;
            tag = bp[t * NK + tag];
        }
    }
}

extern "C" void kernel_launch(void* const* d_in, const int* in_sizes, int n_in,
                              void* d_out, int out_size, void* d_ws, size_t ws_size,
                              hipStream_t stream) {
    (void)in_sizes; (void)n_in; (void)d_ws; (void)ws_size; (void)out_size;
    const float* feats = (const float*)d_in[0];
    const float* trans = (const float*)d_in[1];
    float* out = (float*)d_out;
    crf_fused<<<dim3(NB), dim3(128), 0, stream>>>(feats, trans, out);
}